// Round 1
// baseline (1496.573 us; speedup 1.0000x reference)
//
#include <hip/hip_runtime.h>
#include <math.h>

// Problem constants (N,C,H,W) = (8,64,256,256)
constexpr int Nn  = 8;
constexpr int Cc  = 64;
constexpr int HWp = 65536;           // H*W
constexpr int TPB = 256;             // threads per block
constexpr int PPT = 8;               // pixels per thread in heavy kernels
constexpr int PIXB = TPB * PPT;      // 2048 pixels per block
constexpr int CHUNKS = HWp / PIXB;   // 32

// ---------- helpers ----------
__device__ inline unsigned fkey(float f) {
  unsigned u = __float_as_uint(f);
  return (u & 0x80000000u) ? ~u : (u | 0x80000000u);  // order-preserving float->uint
}
__device__ inline float funkey(unsigned k) {
  return __uint_as_float((k & 0x80000000u) ? (k & 0x7fffffffu) : ~k);
}
__device__ inline float wmax(float v) {
#pragma unroll
  for (int m = 32; m; m >>= 1) v = fmaxf(v, __shfl_xor(v, m, 64));
  return v;
}
__device__ inline float wsum(float v) {
#pragma unroll
  for (int m = 32; m; m >>= 1) v += __shfl_xor(v, m, 64);
  return v;
}
__device__ inline float silu_(float z) { return z / (1.f + __expf(-z)); }

// ---------- k1: per-pixel conv (max+sum over pixels) + key pre-softmax ----------
__global__ __launch_bounds__(TPB, 2) void k1_stats(
    const float* __restrict__ xrgb, const float* __restrict__ xir,
    const float* __restrict__ conv_w, const float* __restrict__ conv_b,
    const float* __restrict__ key_w, const float* __restrict__ key_g,
    const float* __restrict__ key_b, const float* __restrict__ key_m,
    const float* __restrict__ key_v,
    float* __restrict__ kpre, unsigned* __restrict__ mxk,
    float* __restrict__ smo, unsigned* __restrict__ kmaxk)
{
  const int side = blockIdx.z, n = blockIdx.y, chunk = blockIdx.x;
  const float* x = (side ? xir : xrgb) + (size_t)n * Cc * HWp;
  const float ks = key_g[0] * rsqrtf(key_v[0] + 1e-5f);
  const float kb = key_b[0] - key_m[0] * ks;
  float mx[64], sms[64];
#pragma unroll
  for (int o = 0; o < 64; o++) { mx[o] = -1e30f; sms[o] = 0.f; }
  float kml = -1e30f;
  float* kp = kpre + (size_t)(side * Nn + n) * HWp;
  const int e0 = chunk * PIXB + threadIdx.x;
#pragma unroll 1
  for (int i = 0; i < PPT; i++) {
    const int e = e0 + i * TPB;
    float xv[64];
#pragma unroll
    for (int c = 0; c < 64; c++) xv[c] = x[(size_t)c * HWp + e];
    // key conv (1xC) + BN + SiLU
    float kd = 0.f;
#pragma unroll
    for (int c = 0; c < 64; c++) kd += key_w[c] * xv[c];
    float ka = silu_(ks * kd + kb);
    kp[e] = ka;
    kml = fmaxf(kml, ka);
    // main conv: per-o accumulate max & sum (mean path = sum/HW)
#pragma unroll
    for (int o = 0; o < 64; o++) {
      float acc = conv_b[o];
#pragma unroll
      for (int c = 0; c < 64; c++) acc += conv_w[o * 64 + c] * xv[c];
      mx[o] = fmaxf(mx[o], acc);
      sms[o] += acc;
    }
  }
  const int lane = threadIdx.x & 63;
  const int base = (side * Nn + n) * 64;
#pragma unroll
  for (int o = 0; o < 64; o++) {
    float m1 = wmax(mx[o]);
    float s1 = wsum(sms[o]);
    if (lane == 0) {
      atomicMax(&mxk[base + o], fkey(m1));
      atomicAdd(&smo[base + o], s1);
    }
  }
  float km = wmax(kml);
  if (lane == 0) atomicMax(&kmaxk[side * Nn + n], fkey(km));
}

// ---------- k2: key softmax denominator ----------
__global__ void k2_ksum(const float* __restrict__ kpre,
                        const unsigned* __restrict__ kmaxk,
                        float* __restrict__ ksum)
{
  const int sn = blockIdx.x;  // side*N+n, 0..15
  const float kmax = funkey(kmaxk[sn]);
  const float* kp = kpre + (size_t)sn * HWp;
  const int lo = blockIdx.y * 8192, hi = lo + 8192;
  float s = 0.f;
  for (int e = lo + threadIdx.x; e < hi; e += TPB) s += __expf(kp[e] - kmax);
  s = wsum(s);
  __shared__ float red[4];
  const int w = threadIdx.x >> 6, lane = threadIdx.x & 63;
  if (lane == 0) red[w] = s;
  __syncthreads();
  if (threadIdx.x == 0) atomicAdd(&ksum[sn], red[0] + red[1] + red[2] + red[3]);
}

// ---------- k3: avg/max softmax over channels + val-BN constants ----------
__global__ void k3_fin(const float* __restrict__ smo, const unsigned* __restrict__ mxk,
                       const float* __restrict__ val_g, const float* __restrict__ val_b,
                       const float* __restrict__ val_m, const float* __restrict__ val_v,
                       float* __restrict__ avg, float* __restrict__ mxs,
                       float* __restrict__ vs_arr, float* __restrict__ vb_arr)
{
  const int sn = blockIdx.x, o = threadIdx.x;  // 64 threads = 1 wave
  if (sn == 0) {
    float s = val_g[o] * rsqrtf(val_v[o] + 1e-5f);
    vs_arr[o] = s;
    vb_arr[o] = val_b[o] - val_m[o] * s;
  }
  float lm = smo[sn * 64 + o] * (1.f / HWp);
  float M = wmax(lm);
  float E = __expf(lm - M);
  float S = wsum(E);
  avg[sn * 64 + o] = E / S;
  float mm = funkey(mxk[sn * 64 + o]);
  M = wmax(mm);
  E = __expf(mm - M);
  S = wsum(E);
  mxs[sn * 64 + o] = E / S;
}

// ---------- k4: val conv on-the-fly + fea/avgm/maxm contractions + half ----------
__global__ __launch_bounds__(TPB, 2) void k4_val(
    const float* __restrict__ xrgb, const float* __restrict__ xir,
    const float* __restrict__ val_w,
    const float* __restrict__ vs_arr, const float* __restrict__ vb_arr,
    const float* __restrict__ avg, const float* __restrict__ mxs,
    const float* __restrict__ kpre, const unsigned* __restrict__ kmaxk,
    const float* __restrict__ ksum,
    const float* __restrict__ half_w, const float* __restrict__ half_g,
    const float* __restrict__ half_b, const float* __restrict__ half_m,
    const float* __restrict__ half_v,
    float* __restrict__ halfb, float* __restrict__ fea)
{
  const int me = blockIdx.z, n = blockIdx.y, chunk = blockIdx.x;
  // v comes from the OTHER side's features; stats/key/half/fea belong to `me`
  const float* xo = (me ? xrgb : xir) + (size_t)n * Cc * HWp;
  const int sn = me * Nn + n;
  const float kmax = funkey(kmaxk[sn]);
  const float kinv = 1.f / ksum[sn];
  const float* kp = kpre + (size_t)sn * HWp;
  const float hs = half_g[0] * rsqrtf(half_v[0] + 1e-5f);
  const float hb = half_b[0] - half_m[0] * hs;
  const float hw0 = half_w[0], hw1 = half_w[1];
  float* hp = halfb + (size_t)sn * HWp;
  float feap[64];
#pragma unroll
  for (int o = 0; o < 64; o++) feap[o] = 0.f;
  const int e0 = chunk * PIXB + threadIdx.x;
#pragma unroll 1
  for (int i = 0; i < PPT; i++) {
    const int e = e0 + i * TPB;
    float xv[64];
#pragma unroll
    for (int c = 0; c < 64; c++) xv[c] = xo[(size_t)c * HWp + e];
    const float kw = __expf(kp[e] - kmax) * kinv;
    float am = 0.f, mm = 0.f;
#pragma unroll
    for (int o = 0; o < 64; o++) {
      float acc = 0.f;
#pragma unroll
      for (int c = 0; c < 64; c++) acc += val_w[o * 64 + c] * xv[c];
      float v = silu_(vs_arr[o] * acc + vb_arr[o]);
      am += avg[sn * 64 + o] * v;
      mm += mxs[sn * 64 + o] * v;
      feap[o] += v * kw;
    }
    hp[e] = silu_(hs * (hw0 * am + hw1 * mm) + hb);
  }
  const int lane = threadIdx.x & 63;
#pragma unroll
  for (int o = 0; o < 64; o++) {
    float s1 = wsum(feap[o]);
    if (lane == 0) atomicAdd(&fea[sn * 64 + o], s1);
  }
}

// ---------- k5: gate = sigmoid(LN(fea @ convb_w^T)) ----------
__global__ void k5_gate(const float* __restrict__ fea, const float* __restrict__ convb_w,
                        const float* __restrict__ ln_g, const float* __restrict__ ln_b,
                        float* __restrict__ gate)
{
  const int sn = blockIdx.x, o = threadIdx.x;  // 64 threads = 1 wave
  float z = 0.f;
#pragma unroll
  for (int c = 0; c < 64; c++) z += convb_w[o * 64 + c] * fea[sn * 64 + c];
  float mu = wsum(z) * (1.f / 64);
  float d = z - mu;
  float var = wsum(d * d) * (1.f / 64);
  float g = d * rsqrtf(var + 1e-5f) * ln_g[o] + ln_b[o];
  gate[sn * 64 + o] = 1.f / (1.f + __expf(-g));
}

// ---------- k6: out = gate*half + x (streaming, float4) ----------
__global__ __launch_bounds__(256) void k6_out(
    const float* __restrict__ xrgb, const float* __restrict__ xir,
    const float* __restrict__ gate, const float* __restrict__ halfb,
    float* __restrict__ out)
{
  const size_t t = (size_t)blockIdx.x * 256 + threadIdx.x;  // float4 index
  const int e4 = (int)(t & (HWp / 4 - 1));
  size_t r = t >> 14;
  const int c = (int)(r & 63); r >>= 6;
  const int n = (int)(r & 7);
  const int me = (int)(r >> 3);
  const float* x = me ? xir : xrgb;
  const float4 xv = ((const float4*)x)[(((size_t)n * 64 + c) << 14) + e4];
  const float g = gate[(me * 8 + n) * 64 + c];
  const float4 h = ((const float4*)halfb)[((size_t)(me * 8 + n) << 14) + e4];
  float4 ov;
  ov.x = g * h.x + xv.x;
  ov.y = g * h.y + xv.y;
  ov.z = g * h.z + xv.z;
  ov.w = g * h.w + xv.w;
  ((float4*)out)[t] = ov;
}

extern "C" void kernel_launch(void* const* d_in, const int* in_sizes, int n_in,
                              void* d_out, int out_size, void* d_ws, size_t ws_size,
                              hipStream_t stream)
{
  const float* xrgb   = (const float*)d_in[0];
  const float* xir    = (const float*)d_in[1];
  const float* conv_w = (const float*)d_in[2];
  const float* conv_b = (const float*)d_in[3];
  const float* key_w  = (const float*)d_in[4];
  const float* key_g  = (const float*)d_in[5];
  const float* key_b  = (const float*)d_in[6];
  const float* key_m  = (const float*)d_in[7];
  const float* key_v  = (const float*)d_in[8];
  const float* val_w  = (const float*)d_in[9];
  const float* val_g  = (const float*)d_in[10];
  const float* val_b  = (const float*)d_in[11];
  const float* val_m  = (const float*)d_in[12];
  const float* val_v  = (const float*)d_in[13];
  const float* convb_w= (const float*)d_in[14];
  const float* half_w = (const float*)d_in[15];
  const float* half_g = (const float*)d_in[16];
  const float* half_b = (const float*)d_in[17];
  const float* half_m = (const float*)d_in[18];
  const float* half_v = (const float*)d_in[19];
  const float* ln_g   = (const float*)d_in[20];
  const float* ln_b   = (const float*)d_in[21];

  // workspace layout (floats): ~8.4 MiB total
  float* ws      = (float*)d_ws;
  float* kpre    = ws;                    // [2][8][HW]  = 1048576
  float* halfb   = kpre + 2 * Nn * HWp;   // [2][8][HW]  = 1048576
  float* smo     = halfb + 2 * Nn * HWp;  // [2][8][64]
  unsigned* mxk  = (unsigned*)(smo + 1024);   // [2][8][64]
  unsigned* kmaxk= mxk + 1024;            // [2][8]
  float* ksum    = (float*)(kmaxk + 16);  // [2][8]
  float* fea     = ksum + 16;             // [2][8][64]
  float* avg     = fea + 1024;            // [2][8][64]
  float* mxs     = avg + 1024;            // [2][8][64]
  float* gate    = mxs + 1024;            // [2][8][64]
  float* vs_arr  = gate + 1024;           // [64]
  float* vb_arr  = vs_arr + 64;           // [64]

  // zero accumulators (smo, mxk, kmaxk, ksum, fea are contiguous)
  hipMemsetAsync(smo, 0, (size_t)(1024 + 1024 + 16 + 16 + 1024) * sizeof(float), stream);

  dim3 gHeavy(CHUNKS, Nn, 2);
  k1_stats<<<gHeavy, TPB, 0, stream>>>(xrgb, xir, conv_w, conv_b, key_w, key_g, key_b,
                                       key_m, key_v, kpre, mxk, smo, kmaxk);
  k2_ksum<<<dim3(16, 8), TPB, 0, stream>>>(kpre, kmaxk, ksum);
  k3_fin<<<16, 64, 0, stream>>>(smo, mxk, val_g, val_b, val_m, val_v, avg, mxs, vs_arr, vb_arr);
  k4_val<<<gHeavy, TPB, 0, stream>>>(xrgb, xir, val_w, vs_arr, vb_arr, avg, mxs, kpre,
                                     kmaxk, ksum, half_w, half_g, half_b, half_m, half_v,
                                     halfb, fea);
  k5_gate<<<16, 64, 0, stream>>>(fea, convb_w, ln_g, ln_b, gate);
  k6_out<<<(2 * Nn * Cc * HWp / 4) / 256, 256, 0, stream>>>(xrgb, xir, gate, halfb,
                                                            (float*)d_out);
}